// Round 15
// baseline (185.982 us; speedup 1.0000x reference)
//
#include <hip/hip_runtime.h>
#include <cstdint>
#include <math.h>

typedef _Float16 f16;
typedef _Float16 f16x2 __attribute__((ext_vector_type(2)));
typedef _Float16 f16x4 __attribute__((ext_vector_type(4)));
typedef _Float16 f16x8 __attribute__((ext_vector_type(8)));
typedef __fp16   h16x2 __attribute__((ext_vector_type(2)));
typedef float    f32x4 __attribute__((ext_vector_type(4)));

__device__ __forceinline__ f32x4 mfma16(f16x8 a, f16x8 b, f32x4 c) {
  return __builtin_amdgcn_mfma_f32_16x16x32_f16(a, b, c, 0, 0, 0);
}
__device__ __forceinline__ void gl2lds16(const f16* g, f16* l) {
  __builtin_amdgcn_global_load_lds((__attribute__((address_space(1))) void*)(g),
                                   (__attribute__((address_space(3))) void*)(l),
                                   16, 0, 0);
}
__device__ __forceinline__ float fexp2(float x) { return __builtin_amdgcn_exp2f(x); }
__device__ __forceinline__ f16x2 pkrtz(float a, float b) {
  h16x2 r = __builtin_amdgcn_cvt_pkrtz(a, b);
  return __builtin_bit_cast(f16x2, r);
}

// ---------------- fp32 -> f16 conversion ----------------
// Dense 1D grid: 4096 fully-active blocks.
__global__ __launch_bounds__(256) void cvt_kernel(
    const float* __restrict__ x,  const float* __restrict__ wq, const float* __restrict__ wk,
    const float* __restrict__ wv, const float* __restrict__ wo,
    f16* __restrict__ xh, f16* __restrict__ wqkvh, f16* __restrict__ woh)
{
  const int blk = blockIdx.x;
  const float* src; f16* dst; int off;
  if (blk < 2048)      { src = x;  dst = xh;              off = blk; }
  else {
    const int wseg = (blk - 2048) >> 9;       // 0..3
    off = (blk - 2048) & 511;
    if      (wseg == 0) { src = wq; dst = wqkvh; }
    else if (wseg == 1) { src = wk; dst = wqkvh + 1048576; }
    else if (wseg == 2) { src = wv; dst = wqkvh + 2097152; }
    else                { src = wo; dst = woh; }
  }
  const int idx = off * 2048 + (int)threadIdx.x * 8;
  f32x4 a = *(const f32x4*)(src + idx);
  f32x4 b = *(const f32x4*)(src + idx + 4);
  f16x8 h;
  h[0] = (f16)a[0]; h[1] = (f16)a[1]; h[2] = (f16)a[2]; h[3] = (f16)a[3];
  h[4] = (f16)b[0]; h[5] = (f16)b[1]; h[6] = (f16)b[2]; h[7] = (f16)b[3];
  *(f16x8*)(dst + idx) = h;
}

// ---------------- QKV GEMM: 128x128 tile, BK=32, dbuf 1-barrier ----------
// Q AND V written transposed [bh][d][s] with packed f16x4 stores; K stays
// [bh][s][d] (attn stages K per-iteration with f16x8 row loads).
__global__ __launch_bounds__(256) void gemm_qkv(
    const f16* __restrict__ A, const f16* __restrict__ B,
    const float* __restrict__ bias0, const float* __restrict__ bias1, const float* __restrict__ bias2,
    f16* __restrict__ Qtp, f16* __restrict__ Kp, f16* __restrict__ Vtp)
{
  constexpr int K = 1024;
  __shared__ __align__(16) f16 As[2][128 * 32];
  __shared__ __align__(16) f16 Bs[2][128 * 32];
  const int tid  = threadIdx.x;
  const int wave = tid >> 6, lane = tid & 63;
  const int quad = lane >> 4, col = lane & 15;
  const int tile_m = blockIdx.y * 128, tile_n = blockIdx.x * 128;
  const int mb = (wave >> 1) * 64, nb = (wave & 1) * 64;
  const int srow = lane >> 2, scol = (lane & 3) * 8;
  const f16* gA = A + (size_t)(tile_m + wave * 32 + srow) * K + scol;
  const f16* gB = B + (size_t)(tile_n + wave * 32 + srow) * K + scol;

  auto stage = [&](int buf, int k0) {
    gl2lds16(gA + k0,          &As[buf][wave * 1024]);
    gl2lds16(gA + 16 * K + k0, &As[buf][wave * 1024 + 512]);
    gl2lds16(gB + k0,          &Bs[buf][wave * 1024]);
    gl2lds16(gB + 16 * K + k0, &Bs[buf][wave * 1024 + 512]);
  };

  f32x4 acc[4][4] = {};
  stage(0, 0);
  for (int k0 = 0; k0 < K; k0 += 32) {
    const int cur = (k0 >> 5) & 1;
    __syncthreads();                     // buf[cur] landed (barrier drains vmcnt)
    if (k0 + 32 < K) stage(cur ^ 1, k0 + 32);   // overlap with compute below
    f16x8 af[4], bf[4];
    #pragma unroll
    for (int i = 0; i < 4; ++i)
      af[i] = *(const f16x8*)&As[cur][(mb + i * 16 + col) * 32 + quad * 8];
    #pragma unroll
    for (int j = 0; j < 4; ++j)
      bf[j] = *(const f16x8*)&Bs[cur][(nb + j * 16 + col) * 32 + quad * 8];
    #pragma unroll
    for (int i = 0; i < 4; ++i)
      #pragma unroll
      for (int j = 0; j < 4; ++j)
        acc[i][j] = mfma16(af[i], bf[j], acc[i][j]);
  }

  #pragma unroll
  for (int j = 0; j < 4; ++j) {
    const int gn = tile_n + nb + j * 16 + col;
    const int which = gn >> 10;
    const int d = gn & 1023;
    const int h = d >> 6, hi = d & 63;
    if (which != 1) {
      // Q/V -> transposed [bb][h][hi][s], packed f16x4 along s
      const float* bp = (which == 0) ? bias0 : bias2;
      f16* dst        = (which == 0) ? Qtp  : Vtp;
      const float bvv = bp[d];
      const float qs  = (which == 0) ? 0.18033688f : 1.0f;  // 1/sqrt(64)*log2(e) in Q
      #pragma unroll
      for (int i = 0; i < 4; ++i) {
        const int gm = tile_m + mb + i * 16 + quad * 4;   // r=0; s run of 4
        const int bb = gm >> 11, s = gm & 2047;
        f16x4 pw;
        #pragma unroll
        for (int r = 0; r < 4; ++r) pw[r] = (f16)((acc[i][j][r] + bvv) * qs);
        *(f16x4*)&dst[(((size_t)bb * 16 + h) * 64 + hi) * 2048 + s] = pw;
      }
    } else {
      const float bvv = bias1[d];
      #pragma unroll
      for (int i = 0; i < 4; ++i) {
        #pragma unroll
        for (int r = 0; r < 4; ++r) {
          const int gm = tile_m + mb + i * 16 + quad * 4 + r;
          const int bb = gm >> 11, s = gm & 2047;
          Kp[(((size_t)bb * 16 + h) * 2048 + s) * 64 + hi] = (f16)(acc[i][j][r] + bvv);
        }
      }
    }
  }
}

// ---------------- flash attention, merged tile-pair, static-max softmax ----
// R14 body + l-via-MFMA: the row-sum l = P @ ones is computed by the matrix
// pipe (zl = mfma(apa, ones8, zl), 2 MFMAs per active tile, reusing loaded
// apa frags) instead of 16 serial dot2 on the VALU critical path. D-layout
// gives lane (quad,col) l[q=quad*4+r] replicated across cols -> epilogue
// needs ZERO shuffles (was 2 shfl_xor + 4 shfl per tile).
__global__ __launch_bounds__(256, 4) void attn_kernel(
    const f16* __restrict__ Qt, const f16* __restrict__ K, const f16* __restrict__ Vt,
    f16* __restrict__ ctx)
{
  __shared__ __align__(16) f16 Ks[2][64 * 72];     // [buf][kv][d], pad 72
  __shared__ __align__(16) f16 Vts[2][64 * 72];    // [buf][d][kv], pad 72
  __shared__ __align__(16) f16 Ps[4][2][16 * 72];  // per-wave, per-tile P

  const int bh  = blockIdx.x;                      // x = bh -> XCD = bh%8 (R6)
  const int yy  = blockIdx.y;
  const int p   = (yy < 8) ? yy : 23 - yy;         // CU pair (yy,yy+8): p+p'=15
  const int qlong = 31 - p, qshort = p;
  const int tid = threadIdx.x;
  const int wave = tid >> 6, lane = tid & 63;
  const int quad = lane >> 4, col = lane & 15;
  const int b = bh >> 4, h = bh & 15;
  const size_t base = (size_t)bh * 2048 * 64;
  const size_t vtb  = (size_t)bh * 64 * 2048;      // also Qt base stride

  // staging map: 512 16B-chunks per tensor, 2 per thread
  int srow[2], sc8[2];
  #pragma unroll
  for (int i = 0; i < 2; ++i) {
    const int flat = tid + i * 256;
    srow[i] = flat >> 3;
    sc8[i]  = (flat & 7) * 8;
  }

  const int qa = qlong * 64 + wave * 16;    // long tile rows (always active)
  const int qb = qshort * 64 + wave * 16;   // short tile rows (active t<=qshort)
  // Q fragments from transposed layout: element j at d = (quad*8+j), s = q
  f16x8 bqa0, bqa1, bqb0, bqb1;
  #pragma unroll
  for (int j = 0; j < 8; ++j) {
    const size_t r0 = vtb + (size_t)(quad * 8 + j) * 2048;
    const size_t r1 = vtb + (size_t)(32 + quad * 8 + j) * 2048;
    bqa0[j] = Qt[r0 + qa + col];
    bqa1[j] = Qt[r1 + qa + col];
    bqb0[j] = Qt[r0 + qb + col];
    bqb1[j] = Qt[r1 + qb + col];
  }

  // all-ones B-operand for the l-column MFMA
  f16x8 ones8;
  #pragma unroll
  for (int j = 0; j < 8; ++j) ones8[j] = (f16)1.f;

  f32x4 cta[4] = {}, ctb[4] = {};
  f32x4 zla = {}, zlb = {};                 // l accumulators (per-lane, no shuffles)

  f16x8 kr[2], vr[2];
  auto gload = [&](int t) {
    #pragma unroll
    for (int i = 0; i < 2; ++i) {
      kr[i] = *(const f16x8*)&K[base + (size_t)(t * 64 + srow[i]) * 64 + sc8[i]];
      vr[i] = *(const f16x8*)&Vt[vtb + (size_t)srow[i] * 2048 + t * 64 + sc8[i]];
    }
  };
  auto swrite = [&](int buf) {
    #pragma unroll
    for (int i = 0; i < 2; ++i) {
      *(f16x8*)&Ks[buf][srow[i] * 72 + sc8[i]]  = kr[i];
      *(f16x8*)&Vts[buf][srow[i] * 72 + sc8[i]] = vr[i];
    }
  };

  const int nIter = qlong + 1;               // 17..32

  // prologue: stage tile 0 into buf0, prefetch tile 1 into regs
  gload(0);
  __syncthreads();
  swrite(0);
  gload(1);                                  // nIter >= 17 always

  for (int t = 0; t < nIter; ++t) {
    const int cur = t & 1;
    __syncthreads();                         // buf[cur] staged; swrites drained
    const bool doB = (t <= qshort);

    // S^T = K Q^T for both tiles; ak frags shared from registers
    f32x4 sa[4], sb[4];
    __builtin_amdgcn_s_setprio(1);
    #pragma unroll
    for (int jt = 0; jt < 4; ++jt) {
      const int kro = (jt * 16 + col) * 72;
      const f16x8 ak0 = *(const f16x8*)&Ks[cur][kro + quad * 8];
      const f16x8 ak1 = *(const f16x8*)&Ks[cur][kro + 32 + quad * 8];
      f32x4 za = {};
      za = mfma16(ak0, bqa0, za);
      sa[jt] = mfma16(ak1, bqa1, za);
      if (doB) {
        f32x4 zb = {};
        zb = mfma16(ak0, bqb0, zb);
        sb[jt] = mfma16(ak1, bqb1, zb);
      }
    }
    __builtin_amdgcn_s_setprio(0);

    if (t == qlong) {   // long tile diagonal (last iteration)
      #pragma unroll
      for (int jt = 0; jt < 4; ++jt) {
        const int kg = t * 64 + jt * 16 + quad * 4;
        #pragma unroll
        for (int r = 0; r < 4; ++r)
          if (kg + r > qa + col) sa[jt][r] = -1e30f;
      }
    }
    if (t == qshort) {  // short tile diagonal
      #pragma unroll
      for (int jt = 0; jt < 4; ++jt) {
        const int kg = t * 64 + jt * 16 + quad * 4;
        #pragma unroll
        for (int r = 0; r < 4; ++r)
          if (kg + r > qb + col) sb[jt][r] = -1e30f;
      }
    }

    // ---- P = exp2(s) (static-max), long tile -> Ps slot 0 ----
    #pragma unroll
    for (int jt = 0; jt < 4; ++jt) {
      const f16x2 a01 = pkrtz(fexp2(sa[jt][0]), fexp2(sa[jt][1]));
      const f16x2 a23 = pkrtz(fexp2(sa[jt][2]), fexp2(sa[jt][3]));
      f16x4 pw; pw[0] = a01[0]; pw[1] = a01[1]; pw[2] = a23[0]; pw[3] = a23[1];
      *(f16x4*)&Ps[wave][0][col * 72 + jt * 16 + quad * 4] = pw;
    }

    // ---- P = exp2(s), short tile -> Ps slot 1 ----
    if (doB) {
      #pragma unroll
      for (int jt = 0; jt < 4; ++jt) {
        const f16x2 a01 = pkrtz(fexp2(sb[jt][0]), fexp2(sb[jt][1]));
        const f16x2 a23 = pkrtz(fexp2(sb[jt][2]), fexp2(sb[jt][3]));
        f16x4 pw; pw[0] = a01[0]; pw[1] = a01[1]; pw[2] = a23[0]; pw[3] = a23[1];
        *(f16x4*)&Ps[wave][1][col * 72 + jt * 16 + quad * 4] = pw;
      }
    }

    __asm__ volatile("s_waitcnt lgkmcnt(0)" ::: "memory");  // P RAW drain (no swrites in queue)

    // P fragments for PV + l
    const f16x8 apa0 = *(const f16x8*)&Ps[wave][0][col * 72 + quad * 8];
    const f16x8 apa1 = *(const f16x8*)&Ps[wave][0][col * 72 + 32 + quad * 8];

    // stage next tile + refill regs here: ds_writes overlap the PV phase,
    // drained by the next top-of-loop __syncthreads
    if (t + 1 < nIter) {
      swrite(cur ^ 1);
      if (t + 2 < nIter) gload(t + 2);
    }

    // ---- ctx += P V ; l += P @ 1 (matrix pipe) ----
    __builtin_amdgcn_s_setprio(1);
    zla = mfma16(apa1, ones8, mfma16(apa0, ones8, zla));
    if (doB) {
      const f16x8 apb0 = *(const f16x8*)&Ps[wave][1][col * 72 + quad * 8];
      const f16x8 apb1 = *(const f16x8*)&Ps[wave][1][col * 72 + 32 + quad * 8];
      zlb = mfma16(apb1, ones8, mfma16(apb0, ones8, zlb));
      #pragma unroll
      for (int jd = 0; jd < 4; ++jd) {
        const int vro = (jd * 16 + col) * 72;
        const f16x8 bv0 = *(const f16x8*)&Vts[cur][vro + quad * 8];
        const f16x8 bv1 = *(const f16x8*)&Vts[cur][vro + 32 + quad * 8];
        cta[jd] = mfma16(apa1, bv1, mfma16(apa0, bv0, cta[jd]));
        ctb[jd] = mfma16(apb1, bv1, mfma16(apb0, bv0, ctb[jd]));
      }
    } else {
      #pragma unroll
      for (int jd = 0; jd < 4; ++jd) {
        const int vro = (jd * 16 + col) * 72;
        const f16x8 bv0 = *(const f16x8*)&Vts[cur][vro + quad * 8];
        const f16x8 bv1 = *(const f16x8*)&Vts[cur][vro + 32 + quad * 8];
        cta[jd] = mfma16(apa1, bv1, mfma16(apa0, bv0, cta[jd]));
      }
    }
    __builtin_amdgcn_s_setprio(0);
  }

  // ---- epilogue: zl[r] = l[q=quad*4+r] directly (no shuffles) ----
  #pragma unroll
  for (int jd = 0; jd < 4; ++jd) {
    #pragma unroll
    for (int r = 0; r < 4; ++r) {
      const int qga = qa + quad * 4 + r;
      const int qgb = qb + quad * 4 + r;
      const int d = h * 64 + jd * 16 + col;
      ctx[((size_t)b * 2048 + qga) * 1024 + d] = (f16)(cta[jd][r] / zla[r]);
      ctx[((size_t)b * 2048 + qgb) * 1024 + d] = (f16)(ctb[jd][r] / zlb[r]);
    }
  }
}

// ---------------- O projection: 128x64 tile, BK=64, dbuf 1-barrier --------
// Unchanged from R11/R13 (known-good).
__global__ __launch_bounds__(256) void gemm_o(
    const f16* __restrict__ A, const f16* __restrict__ B, const float* __restrict__ bias,
    float* __restrict__ Out)
{
  constexpr int K = 1024;
  __shared__ __align__(16) f16 As[2][2][128 * 32];   // [buf][ks][row][32]
  __shared__ __align__(16) f16 Bs[2][2][64 * 32];    // [buf][ks][row][32]
  const int tid  = threadIdx.x;
  const int wave = tid >> 6, lane = tid & 63;
  const int quad = lane >> 4, col = lane & 15;
  const int tile_m = blockIdx.y * 128, tile_n = blockIdx.x * 64;
  const int mb = wave * 32;
  const int srow = lane >> 2, scol = (lane & 3) * 8;   // 16 rows x 32 cols per call
  const f16* gA = A + (size_t)(tile_m + srow) * K + scol;
  const f16* gB = B + (size_t)(tile_n + srow) * K + scol;

  auto stage = [&](int buf, int k0) {
    #pragma unroll
    for (int ks = 0; ks < 2; ++ks) {
      #pragma unroll
      for (int i = 0; i < 2; ++i)      // A: this wave's 32 rows, 16 per call
        gl2lds16(gA + (size_t)(wave * 32 + i * 16) * K + k0 + ks * 32,
                 &As[buf][ks][(wave * 32 + i * 16) * 32]);
      // B: this wave's 16 rows
      gl2lds16(gB + (size_t)(wave * 16) * K + k0 + ks * 32,
               &Bs[buf][ks][(wave * 16) * 32]);
    }
  };

  f32x4 acc[2][4] = {};
  stage(0, 0);
  for (int k0 = 0; k0 < K; k0 += 64) {
    const int cur = (k0 >> 6) & 1;
    __syncthreads();                     // buf[cur] landed (barrier drains vmcnt)
    if (k0 + 64 < K) stage(cur ^ 1, k0 + 64);
    #pragma unroll
    for (int ks = 0; ks < 2; ++ks) {
      f16x8 af[2], bf[4];
      #pragma unroll
      for (int i = 0; i < 2; ++i)
        af[i] = *(const f16x8*)&As[cur][ks][(mb + i * 16 + col) * 32 + quad * 8];
      #pragma unroll
      for (int j = 0; j < 4; ++j)
        bf[j] = *(const f16x8*)&Bs[cur][ks][(j * 16 + col) * 32 + quad * 8];
      #pragma unroll
      for (int i = 0; i < 2; ++i)
        #pragma unroll
        for (int j = 0; j < 4; ++j)
          acc[i][j] = mfma16(af[i], bf[j], acc[i][j]);
    }
  }

  #pragma unroll
  for (int j = 0; j < 4; ++j) {
    const int gn = tile_n + j * 16 + col;
    const float bvv = bias[gn];
    #pragma unroll
    for (int i = 0; i < 2; ++i) {
      #pragma unroll
      for (int r = 0; r < 4; ++r) {
        const int gm = tile_m + mb + i * 16 + quad * 4 + r;
        Out[(size_t)gm * 1024 + gn] = acc[i][j][r] + bvv;
      }
    }
  }
}

extern "C" void kernel_launch(void* const* d_in, const int* in_sizes, int n_in,
                              void* d_out, int out_size, void* d_ws, size_t ws_size,
                              hipStream_t stream)
{
  const float* x  = (const float*)d_in[0];
  const float* Wq = (const float*)d_in[1];
  const float* bq = (const float*)d_in[2];
  const float* Wk = (const float*)d_in[3];
  const float* bk = (const float*)d_in[4];
  const float* Wv = (const float*)d_in[5];
  const float* bv = (const float*)d_in[6];
  const float* Wo = (const float*)d_in[7];
  const float* bo = (const float*)d_in[8];
  float* out = (float*)d_out;

  f16* ws = (f16*)d_ws;
  const size_t M1 = 1048576;
  f16* xh    = ws;             // 4M halves
  f16* wqkvh = ws + 4  * M1;   // 3M
  f16* woh   = ws + 7  * M1;   // 1M
  f16* Qth   = ws + 8  * M1;   // 4M  [B,H,64,S] transposed, pre-scaled
  f16* Kh    = ws + 12 * M1;   // 4M  [B,H,S,64]
  f16* Vth   = ws + 20 * M1;   // 4M  [B,H,64,S] (written directly by gemm_qkv)
  f16* ctxh  = ws + 24 * M1;   // 4M  [B,S,D]

  cvt_kernel<<<4096, 256, 0, stream>>>(x, Wq, Wk, Wv, Wo, xh, wqkvh, woh);
  gemm_qkv<<<dim3(24, 32), 256, 0, stream>>>(xh, wqkvh, bq, bk, bv, Qth, Kh, Vth);
  attn_kernel<<<dim3(32, 16), 256, 0, stream>>>(Qth, Kh, Vth, ctxh);
  gemm_o<<<dim3(16, 32), 256, 0, stream>>>(ctxh, woh, bo, out);
}

// Round 16
// 183.961 us; speedup vs baseline: 1.0110x; 1.0110x over previous
//
#include <hip/hip_runtime.h>
#include <cstdint>
#include <math.h>

typedef _Float16 f16;
typedef _Float16 f16x2 __attribute__((ext_vector_type(2)));
typedef _Float16 f16x4 __attribute__((ext_vector_type(4)));
typedef _Float16 f16x8 __attribute__((ext_vector_type(8)));
typedef __fp16   h16x2 __attribute__((ext_vector_type(2)));
typedef float    f32x4 __attribute__((ext_vector_type(4)));

__device__ __forceinline__ f32x4 mfma16(f16x8 a, f16x8 b, f32x4 c) {
  return __builtin_amdgcn_mfma_f32_16x16x32_f16(a, b, c, 0, 0, 0);
}
__device__ __forceinline__ void gl2lds16(const f16* g, f16* l) {
  __builtin_amdgcn_global_load_lds((__attribute__((address_space(1))) void*)(g),
                                   (__attribute__((address_space(3))) void*)(l),
                                   16, 0, 0);
}
__device__ __forceinline__ float fexp2(float x) { return __builtin_amdgcn_exp2f(x); }
__device__ __forceinline__ f16x2 pkrtz(float a, float b) {
  h16x2 r = __builtin_amdgcn_cvt_pkrtz(a, b);
  return __builtin_bit_cast(f16x2, r);
}

// ---------------- fp32 -> f16 conversion ----------------
// Dense 1D grid: 4096 fully-active blocks.
__global__ __launch_bounds__(256) void cvt_kernel(
    const float* __restrict__ x,  const float* __restrict__ wq, const float* __restrict__ wk,
    const float* __restrict__ wv, const float* __restrict__ wo,
    f16* __restrict__ xh, f16* __restrict__ wqkvh, f16* __restrict__ woh)
{
  const int blk = blockIdx.x;
  const float* src; f16* dst; int off;
  if (blk < 2048)      { src = x;  dst = xh;              off = blk; }
  else {
    const int wseg = (blk - 2048) >> 9;       // 0..3
    off = (blk - 2048) & 511;
    if      (wseg == 0) { src = wq; dst = wqkvh; }
    else if (wseg == 1) { src = wk; dst = wqkvh + 1048576; }
    else if (wseg == 2) { src = wv; dst = wqkvh + 2097152; }
    else                { src = wo; dst = woh; }
  }
  const int idx = off * 2048 + (int)threadIdx.x * 8;
  f32x4 a = *(const f32x4*)(src + idx);
  f32x4 b = *(const f32x4*)(src + idx + 4);
  f16x8 h;
  h[0] = (f16)a[0]; h[1] = (f16)a[1]; h[2] = (f16)a[2]; h[3] = (f16)a[3];
  h[4] = (f16)b[0]; h[5] = (f16)b[1]; h[6] = (f16)b[2]; h[7] = (f16)b[3];
  *(f16x8*)(dst + idx) = h;
}

// ---------------- QKV GEMM: 128x128, BK=32, reg-staged 2-phase pipeline ---
// R16: attn's staging discipline ported (regs = 3rd buffer, NO asm fences):
// gload(k+2)->regs during iter k; swrite(k+1) right after barrier(k+1) -- the
// COMPILER inserts the counted vmcnt before the ds_write, and that wait has a
// full iteration of cover (vs gl2lds' single compute phase -> exposed L2
// latency every step; R12's manual vmcnt variant regressed via asm fences).
// LDS stays 2 bufs / 32KB (3 blocks/CU, grid 768 = exactly 3/CU).
__global__ __launch_bounds__(256) void gemm_qkv(
    const f16* __restrict__ A, const f16* __restrict__ B,
    const float* __restrict__ bias0, const float* __restrict__ bias1, const float* __restrict__ bias2,
    f16* __restrict__ Qtp, f16* __restrict__ Kp, f16* __restrict__ Vtp)
{
  constexpr int K = 1024;
  __shared__ __align__(16) f16 As[2][128 * 32];
  __shared__ __align__(16) f16 Bs[2][128 * 32];
  const int tid  = threadIdx.x;
  const int wave = tid >> 6, lane = tid & 63;
  const int quad = lane >> 4, col = lane & 15;
  const int tile_m = blockIdx.y * 128, tile_n = blockIdx.x * 128;
  const int mb = (wave >> 1) * 64, nb = (wave & 1) * 64;
  const int srow = lane >> 2, scol = (lane & 3) * 8;
  const f16* gA = A + (size_t)(tile_m + wave * 32 + srow) * K + scol;
  const f16* gB = B + (size_t)(tile_n + wave * 32 + srow) * K + scol;
  const int lo = wave * 1024 + srow * 32 + scol;   // lane-linear LDS slot

  f16x8 ra0, ra1, rb0, rb1;                 // register staging buffer
  auto gload = [&](int k0) {
    ra0 = *(const f16x8*)(gA + k0);
    ra1 = *(const f16x8*)(gA + 16 * K + k0);
    rb0 = *(const f16x8*)(gB + k0);
    rb1 = *(const f16x8*)(gB + 16 * K + k0);
  };
  auto swrite = [&](int buf) {
    *(f16x8*)&As[buf][lo]       = ra0;
    *(f16x8*)&As[buf][lo + 512] = ra1;
    *(f16x8*)&Bs[buf][lo]       = rb0;
    *(f16x8*)&Bs[buf][lo + 512] = rb1;
  };

  f32x4 acc[4][4] = {};
  gload(0);
  swrite(0);
  gload(32);
  for (int k0 = 0; k0 < K; k0 += 32) {
    const int cur = (k0 >> 5) & 1;
    __syncthreads();                     // buf[cur] staged (lgkm drained)
    if (k0 + 32 < K) {
      swrite(cur ^ 1);                   // regs from prev iter; full-iter vmcnt cover
      if (k0 + 64 < K) gload(k0 + 64);   // refill regs, 2 iterations ahead
    }
    f16x8 af[4], bf[4];
    #pragma unroll
    for (int i = 0; i < 4; ++i)
      af[i] = *(const f16x8*)&As[cur][(mb + i * 16 + col) * 32 + quad * 8];
    #pragma unroll
    for (int j = 0; j < 4; ++j)
      bf[j] = *(const f16x8*)&Bs[cur][(nb + j * 16 + col) * 32 + quad * 8];
    #pragma unroll
    for (int i = 0; i < 4; ++i)
      #pragma unroll
      for (int j = 0; j < 4; ++j)
        acc[i][j] = mfma16(af[i], bf[j], acc[i][j]);
  }

  #pragma unroll
  for (int j = 0; j < 4; ++j) {
    const int gn = tile_n + nb + j * 16 + col;
    const int which = gn >> 10;
    const int d = gn & 1023;
    const int h = d >> 6, hi = d & 63;
    if (which != 1) {
      // Q/V -> transposed [bb][h][hi][s], packed f16x4 along s
      const float* bp = (which == 0) ? bias0 : bias2;
      f16* dst        = (which == 0) ? Qtp  : Vtp;
      const float bvv = bp[d];
      const float qs  = (which == 0) ? 0.18033688f : 1.0f;  // 1/sqrt(64)*log2(e) in Q
      #pragma unroll
      for (int i = 0; i < 4; ++i) {
        const int gm = tile_m + mb + i * 16 + quad * 4;   // r=0; s run of 4
        const int bb = gm >> 11, s = gm & 2047;
        f16x4 pw;
        #pragma unroll
        for (int r = 0; r < 4; ++r) pw[r] = (f16)((acc[i][j][r] + bvv) * qs);
        *(f16x4*)&dst[(((size_t)bb * 16 + h) * 64 + hi) * 2048 + s] = pw;
      }
    } else {
      const float bvv = bias1[d];
      #pragma unroll
      for (int i = 0; i < 4; ++i) {
        #pragma unroll
        for (int r = 0; r < 4; ++r) {
          const int gm = tile_m + mb + i * 16 + quad * 4 + r;
          const int bb = gm >> 11, s = gm & 2047;
          Kp[(((size_t)bb * 16 + h) * 2048 + s) * 64 + hi] = (f16)(acc[i][j][r] + bvv);
        }
      }
    }
  }
}

// ---------------- flash attention, merged tile-pair, static-max softmax ----
// Unchanged from R15 (l-via-MFMA; attn no longer the slowest kernel).
__global__ __launch_bounds__(256, 4) void attn_kernel(
    const f16* __restrict__ Qt, const f16* __restrict__ K, const f16* __restrict__ Vt,
    f16* __restrict__ ctx)
{
  __shared__ __align__(16) f16 Ks[2][64 * 72];     // [buf][kv][d], pad 72
  __shared__ __align__(16) f16 Vts[2][64 * 72];    // [buf][d][kv], pad 72
  __shared__ __align__(16) f16 Ps[4][2][16 * 72];  // per-wave, per-tile P

  const int bh  = blockIdx.x;                      // x = bh -> XCD = bh%8 (R6)
  const int yy  = blockIdx.y;
  const int p   = (yy < 8) ? yy : 23 - yy;         // CU pair (yy,yy+8): p+p'=15
  const int qlong = 31 - p, qshort = p;
  const int tid = threadIdx.x;
  const int wave = tid >> 6, lane = tid & 63;
  const int quad = lane >> 4, col = lane & 15;
  const int b = bh >> 4, h = bh & 15;
  const size_t base = (size_t)bh * 2048 * 64;
  const size_t vtb  = (size_t)bh * 64 * 2048;      // also Qt base stride

  // staging map: 512 16B-chunks per tensor, 2 per thread
  int srow[2], sc8[2];
  #pragma unroll
  for (int i = 0; i < 2; ++i) {
    const int flat = tid + i * 256;
    srow[i] = flat >> 3;
    sc8[i]  = (flat & 7) * 8;
  }

  const int qa = qlong * 64 + wave * 16;    // long tile rows (always active)
  const int qb = qshort * 64 + wave * 16;   // short tile rows (active t<=qshort)
  // Q fragments from transposed layout: element j at d = (quad*8+j), s = q
  f16x8 bqa0, bqa1, bqb0, bqb1;
  #pragma unroll
  for (int j = 0; j < 8; ++j) {
    const size_t r0 = vtb + (size_t)(quad * 8 + j) * 2048;
    const size_t r1 = vtb + (size_t)(32 + quad * 8 + j) * 2048;
    bqa0[j] = Qt[r0 + qa + col];
    bqa1[j] = Qt[r1 + qa + col];
    bqb0[j] = Qt[r0 + qb + col];
    bqb1[j] = Qt[r1 + qb + col];
  }

  // all-ones B-operand for the l-column MFMA
  f16x8 ones8;
  #pragma unroll
  for (int j = 0; j < 8; ++j) ones8[j] = (f16)1.f;

  f32x4 cta[4] = {}, ctb[4] = {};
  f32x4 zla = {}, zlb = {};                 // l accumulators (per-lane, no shuffles)

  f16x8 kr[2], vr[2];
  auto gload = [&](int t) {
    #pragma unroll
    for (int i = 0; i < 2; ++i) {
      kr[i] = *(const f16x8*)&K[base + (size_t)(t * 64 + srow[i]) * 64 + sc8[i]];
      vr[i] = *(const f16x8*)&Vt[vtb + (size_t)srow[i] * 2048 + t * 64 + sc8[i]];
    }
  };
  auto swrite = [&](int buf) {
    #pragma unroll
    for (int i = 0; i < 2; ++i) {
      *(f16x8*)&Ks[buf][srow[i] * 72 + sc8[i]]  = kr[i];
      *(f16x8*)&Vts[buf][srow[i] * 72 + sc8[i]] = vr[i];
    }
  };

  const int nIter = qlong + 1;               // 17..32

  // prologue: stage tile 0 into buf0, prefetch tile 1 into regs
  gload(0);
  __syncthreads();
  swrite(0);
  gload(1);                                  // nIter >= 17 always

  for (int t = 0; t < nIter; ++t) {
    const int cur = t & 1;
    __syncthreads();                         // buf[cur] staged; swrites drained
    const bool doB = (t <= qshort);

    // S^T = K Q^T for both tiles; ak frags shared from registers
    f32x4 sa[4], sb[4];
    __builtin_amdgcn_s_setprio(1);
    #pragma unroll
    for (int jt = 0; jt < 4; ++jt) {
      const int kro = (jt * 16 + col) * 72;
      const f16x8 ak0 = *(const f16x8*)&Ks[cur][kro + quad * 8];
      const f16x8 ak1 = *(const f16x8*)&Ks[cur][kro + 32 + quad * 8];
      f32x4 za = {};
      za = mfma16(ak0, bqa0, za);
      sa[jt] = mfma16(ak1, bqa1, za);
      if (doB) {
        f32x4 zb = {};
        zb = mfma16(ak0, bqb0, zb);
        sb[jt] = mfma16(ak1, bqb1, zb);
      }
    }
    __builtin_amdgcn_s_setprio(0);

    if (t == qlong) {   // long tile diagonal (last iteration)
      #pragma unroll
      for (int jt = 0; jt < 4; ++jt) {
        const int kg = t * 64 + jt * 16 + quad * 4;
        #pragma unroll
        for (int r = 0; r < 4; ++r)
          if (kg + r > qa + col) sa[jt][r] = -1e30f;
      }
    }
    if (t == qshort) {  // short tile diagonal
      #pragma unroll
      for (int jt = 0; jt < 4; ++jt) {
        const int kg = t * 64 + jt * 16 + quad * 4;
        #pragma unroll
        for (int r = 0; r < 4; ++r)
          if (kg + r > qb + col) sb[jt][r] = -1e30f;
      }
    }

    // ---- P = exp2(s) (static-max), long tile -> Ps slot 0 ----
    #pragma unroll
    for (int jt = 0; jt < 4; ++jt) {
      const f16x2 a01 = pkrtz(fexp2(sa[jt][0]), fexp2(sa[jt][1]));
      const f16x2 a23 = pkrtz(fexp2(sa[jt][2]), fexp2(sa[jt][3]));
      f16x4 pw; pw[0] = a01[0]; pw[1] = a01[1]; pw[2] = a23[0]; pw[3] = a23[1];
      *(f16x4*)&Ps[wave][0][col * 72 + jt * 16 + quad * 4] = pw;
    }

    // ---- P = exp2(s), short tile -> Ps slot 1 ----
    if (doB) {
      #pragma unroll
      for (int jt = 0; jt < 4; ++jt) {
        const f16x2 a01 = pkrtz(fexp2(sb[jt][0]), fexp2(sb[jt][1]));
        const f16x2 a23 = pkrtz(fexp2(sb[jt][2]), fexp2(sb[jt][3]));
        f16x4 pw; pw[0] = a01[0]; pw[1] = a01[1]; pw[2] = a23[0]; pw[3] = a23[1];
        *(f16x4*)&Ps[wave][1][col * 72 + jt * 16 + quad * 4] = pw;
      }
    }

    __asm__ volatile("s_waitcnt lgkmcnt(0)" ::: "memory");  // P RAW drain (no swrites in queue)

    // P fragments for PV + l
    const f16x8 apa0 = *(const f16x8*)&Ps[wave][0][col * 72 + quad * 8];
    const f16x8 apa1 = *(const f16x8*)&Ps[wave][0][col * 72 + 32 + quad * 8];

    // stage next tile + refill regs here: ds_writes overlap the PV phase,
    // drained by the next top-of-loop __syncthreads
    if (t + 1 < nIter) {
      swrite(cur ^ 1);
      if (t + 2 < nIter) gload(t + 2);
    }

    // ---- ctx += P V ; l += P @ 1 (matrix pipe) ----
    __builtin_amdgcn_s_setprio(1);
    zla = mfma16(apa1, ones8, mfma16(apa0, ones8, zla));
    if (doB) {
      const f16x8 apb0 = *(const f16x8*)&Ps[wave][1][col * 72 + quad * 8];
      const f16x8 apb1 = *(const f16x8*)&Ps[wave][1][col * 72 + 32 + quad * 8];
      zlb = mfma16(apb1, ones8, mfma16(apb0, ones8, zlb));
      #pragma unroll
      for (int jd = 0; jd < 4; ++jd) {
        const int vro = (jd * 16 + col) * 72;
        const f16x8 bv0 = *(const f16x8*)&Vts[cur][vro + quad * 8];
        const f16x8 bv1 = *(const f16x8*)&Vts[cur][vro + 32 + quad * 8];
        cta[jd] = mfma16(apa1, bv1, mfma16(apa0, bv0, cta[jd]));
        ctb[jd] = mfma16(apb1, bv1, mfma16(apb0, bv0, ctb[jd]));
      }
    } else {
      #pragma unroll
      for (int jd = 0; jd < 4; ++jd) {
        const int vro = (jd * 16 + col) * 72;
        const f16x8 bv0 = *(const f16x8*)&Vts[cur][vro + quad * 8];
        const f16x8 bv1 = *(const f16x8*)&Vts[cur][vro + 32 + quad * 8];
        cta[jd] = mfma16(apa1, bv1, mfma16(apa0, bv0, cta[jd]));
      }
    }
    __builtin_amdgcn_s_setprio(0);
  }

  // ---- epilogue: zl[r] = l[q=quad*4+r] directly (no shuffles) ----
  #pragma unroll
  for (int jd = 0; jd < 4; ++jd) {
    #pragma unroll
    for (int r = 0; r < 4; ++r) {
      const int qga = qa + quad * 4 + r;
      const int qgb = qb + quad * 4 + r;
      const int d = h * 64 + jd * 16 + col;
      ctx[((size_t)b * 2048 + qga) * 1024 + d] = (f16)(cta[jd][r] / zla[r]);
      ctx[((size_t)b * 2048 + qgb) * 1024 + d] = (f16)(ctb[jd][r] / zlb[r]);
    }
  }
}

// ---------------- O projection: 128x64 tile, BK=64, dbuf 1-barrier --------
// Unchanged from R11/R13 (known-good).
__global__ __launch_bounds__(256) void gemm_o(
    const f16* __restrict__ A, const f16* __restrict__ B, const float* __restrict__ bias,
    float* __restrict__ Out)
{
  constexpr int K = 1024;
  __shared__ __align__(16) f16 As[2][2][128 * 32];   // [buf][ks][row][32]
  __shared__ __align__(16) f16 Bs[2][2][64 * 32];    // [buf][ks][row][32]
  const int tid  = threadIdx.x;
  const int wave = tid >> 6, lane = tid & 63;
  const int quad = lane >> 4, col = lane & 15;
  const int tile_m = blockIdx.y * 128, tile_n = blockIdx.x * 64;
  const int mb = wave * 32;
  const int srow = lane >> 2, scol = (lane & 3) * 8;   // 16 rows x 32 cols per call
  const f16* gA = A + (size_t)(tile_m + srow) * K + scol;
  const f16* gB = B + (size_t)(tile_n + srow) * K + scol;

  auto stage = [&](int buf, int k0) {
    #pragma unroll
    for (int ks = 0; ks < 2; ++ks) {
      #pragma unroll
      for (int i = 0; i < 2; ++i)      // A: this wave's 32 rows, 16 per call
        gl2lds16(gA + (size_t)(wave * 32 + i * 16) * K + k0 + ks * 32,
                 &As[buf][ks][(wave * 32 + i * 16) * 32]);
      // B: this wave's 16 rows
      gl2lds16(gB + (size_t)(wave * 16) * K + k0 + ks * 32,
               &Bs[buf][ks][(wave * 16) * 32]);
    }
  };

  f32x4 acc[2][4] = {};
  stage(0, 0);
  for (int k0 = 0; k0 < K; k0 += 64) {
    const int cur = (k0 >> 6) & 1;
    __syncthreads();                     // buf[cur] landed (barrier drains vmcnt)
    if (k0 + 64 < K) stage(cur ^ 1, k0 + 64);
    #pragma unroll
    for (int ks = 0; ks < 2; ++ks) {
      f16x8 af[2], bf[4];
      #pragma unroll
      for (int i = 0; i < 2; ++i)
        af[i] = *(const f16x8*)&As[cur][ks][(mb + i * 16 + col) * 32 + quad * 8];
      #pragma unroll
      for (int j = 0; j < 4; ++j)
        bf[j] = *(const f16x8*)&Bs[cur][ks][(j * 16 + col) * 32 + quad * 8];
      #pragma unroll
      for (int i = 0; i < 2; ++i)
        #pragma unroll
        for (int j = 0; j < 4; ++j)
          acc[i][j] = mfma16(af[i], bf[j], acc[i][j]);
    }
  }

  #pragma unroll
  for (int j = 0; j < 4; ++j) {
    const int gn = tile_n + j * 16 + col;
    const float bvv = bias[gn];
    #pragma unroll
    for (int i = 0; i < 2; ++i) {
      #pragma unroll
      for (int r = 0; r < 4; ++r) {
        const int gm = tile_m + mb + i * 16 + quad * 4 + r;
        Out[(size_t)gm * 1024 + gn] = acc[i][j][r] + bvv;
      }
    }
  }
}

extern "C" void kernel_launch(void* const* d_in, const int* in_sizes, int n_in,
                              void* d_out, int out_size, void* d_ws, size_t ws_size,
                              hipStream_t stream)
{
  const float* x  = (const float*)d_in[0];
  const float* Wq = (const float*)d_in[1];
  const float* bq = (const float*)d_in[2];
  const float* Wk = (const float*)d_in[3];
  const float* bk = (const float*)d_in[4];
  const float* Wv = (const float*)d_in[5];
  const float* bv = (const float*)d_in[6];
  const float* Wo = (const float*)d_in[7];
  const float* bo = (const float*)d_in[8];
  float* out = (float*)d_out;

  f16* ws = (f16*)d_ws;
  const size_t M1 = 1048576;
  f16* xh    = ws;             // 4M halves
  f16* wqkvh = ws + 4  * M1;   // 3M
  f16* woh   = ws + 7  * M1;   // 1M
  f16* Qth   = ws + 8  * M1;   // 4M  [B,H,64,S] transposed, pre-scaled
  f16* Kh    = ws + 12 * M1;   // 4M  [B,H,S,64]
  f16* Vth   = ws + 20 * M1;   // 4M  [B,H,64,S] (written directly by gemm_qkv)
  f16* ctxh  = ws + 24 * M1;   // 4M  [B,S,D]

  cvt_kernel<<<4096, 256, 0, stream>>>(x, Wq, Wk, Wv, Wo, xh, wqkvh, woh);
  gemm_qkv<<<dim3(24, 32), 256, 0, stream>>>(xh, wqkvh, bq, bk, bv, Qth, Kh, Vth);
  attn_kernel<<<dim3(32, 16), 256, 0, stream>>>(Qth, Kh, Vth, ctxh);
  gemm_o<<<dim3(16, 32), 256, 0, stream>>>(ctxh, woh, bo, out);
}

// Round 17
// 178.719 us; speedup vs baseline: 1.0406x; 1.0293x over previous
//
#include <hip/hip_runtime.h>
#include <cstdint>
#include <math.h>

typedef _Float16 f16;
typedef _Float16 f16x2 __attribute__((ext_vector_type(2)));
typedef _Float16 f16x4 __attribute__((ext_vector_type(4)));
typedef _Float16 f16x8 __attribute__((ext_vector_type(8)));
typedef __fp16   h16x2 __attribute__((ext_vector_type(2)));
typedef float    f32x4 __attribute__((ext_vector_type(4)));

__device__ __forceinline__ f32x4 mfma16(f16x8 a, f16x8 b, f32x4 c) {
  return __builtin_amdgcn_mfma_f32_16x16x32_f16(a, b, c, 0, 0, 0);
}
__device__ __forceinline__ float fexp2(float x) { return __builtin_amdgcn_exp2f(x); }
__device__ __forceinline__ f16x2 pkrtz(float a, float b) {
  h16x2 r = __builtin_amdgcn_cvt_pkrtz(a, b);
  return __builtin_bit_cast(f16x2, r);
}

// ---------------- fp32 -> f16 conversion ----------------
// Dense 1D grid: 4096 fully-active blocks.
__global__ __launch_bounds__(256) void cvt_kernel(
    const float* __restrict__ x,  const float* __restrict__ wq, const float* __restrict__ wk,
    const float* __restrict__ wv, const float* __restrict__ wo,
    f16* __restrict__ xh, f16* __restrict__ wqkvh, f16* __restrict__ woh)
{
  const int blk = blockIdx.x;
  const float* src; f16* dst; int off;
  if (blk < 2048)      { src = x;  dst = xh;              off = blk; }
  else {
    const int wseg = (blk - 2048) >> 9;       // 0..3
    off = (blk - 2048) & 511;
    if      (wseg == 0) { src = wq; dst = wqkvh; }
    else if (wseg == 1) { src = wk; dst = wqkvh + 1048576; }
    else if (wseg == 2) { src = wv; dst = wqkvh + 2097152; }
    else                { src = wo; dst = woh; }
  }
  const int idx = off * 2048 + (int)threadIdx.x * 8;
  f32x4 a = *(const f32x4*)(src + idx);
  f32x4 b = *(const f32x4*)(src + idx + 4);
  f16x8 h;
  h[0] = (f16)a[0]; h[1] = (f16)a[1]; h[2] = (f16)a[2]; h[3] = (f16)a[3];
  h[4] = (f16)b[0]; h[5] = (f16)b[1]; h[6] = (f16)b[2]; h[7] = (f16)b[3];
  *(f16x8*)(dst + idx) = h;
}

// ---------------- QKV GEMM: 128x128, BK=32, reg-staged 2-phase pipeline ---
// Unchanged from R16 (verified: dropped out of top-5, total -2us).
__global__ __launch_bounds__(256) void gemm_qkv(
    const f16* __restrict__ A, const f16* __restrict__ B,
    const float* __restrict__ bias0, const float* __restrict__ bias1, const float* __restrict__ bias2,
    f16* __restrict__ Qtp, f16* __restrict__ Kp, f16* __restrict__ Vtp)
{
  constexpr int K = 1024;
  __shared__ __align__(16) f16 As[2][128 * 32];
  __shared__ __align__(16) f16 Bs[2][128 * 32];
  const int tid  = threadIdx.x;
  const int wave = tid >> 6, lane = tid & 63;
  const int quad = lane >> 4, col = lane & 15;
  const int tile_m = blockIdx.y * 128, tile_n = blockIdx.x * 128;
  const int mb = (wave >> 1) * 64, nb = (wave & 1) * 64;
  const int srow = lane >> 2, scol = (lane & 3) * 8;
  const f16* gA = A + (size_t)(tile_m + wave * 32 + srow) * K + scol;
  const f16* gB = B + (size_t)(tile_n + wave * 32 + srow) * K + scol;
  const int lo = wave * 1024 + srow * 32 + scol;   // lane-linear LDS slot

  f16x8 ra0, ra1, rb0, rb1;                 // register staging buffer
  auto gload = [&](int k0) {
    ra0 = *(const f16x8*)(gA + k0);
    ra1 = *(const f16x8*)(gA + 16 * K + k0);
    rb0 = *(const f16x8*)(gB + k0);
    rb1 = *(const f16x8*)(gB + 16 * K + k0);
  };
  auto swrite = [&](int buf) {
    *(f16x8*)&As[buf][lo]       = ra0;
    *(f16x8*)&As[buf][lo + 512] = ra1;
    *(f16x8*)&Bs[buf][lo]       = rb0;
    *(f16x8*)&Bs[buf][lo + 512] = rb1;
  };

  f32x4 acc[4][4] = {};
  gload(0);
  swrite(0);
  gload(32);
  for (int k0 = 0; k0 < K; k0 += 32) {
    const int cur = (k0 >> 5) & 1;
    __syncthreads();                     // buf[cur] staged (lgkm drained)
    if (k0 + 32 < K) {
      swrite(cur ^ 1);                   // regs from prev iter; full-iter vmcnt cover
      if (k0 + 64 < K) gload(k0 + 64);   // refill regs, 2 iterations ahead
    }
    f16x8 af[4], bf[4];
    #pragma unroll
    for (int i = 0; i < 4; ++i)
      af[i] = *(const f16x8*)&As[cur][(mb + i * 16 + col) * 32 + quad * 8];
    #pragma unroll
    for (int j = 0; j < 4; ++j)
      bf[j] = *(const f16x8*)&Bs[cur][(nb + j * 16 + col) * 32 + quad * 8];
    #pragma unroll
    for (int i = 0; i < 4; ++i)
      #pragma unroll
      for (int j = 0; j < 4; ++j)
        acc[i][j] = mfma16(af[i], bf[j], acc[i][j]);
  }

  #pragma unroll
  for (int j = 0; j < 4; ++j) {
    const int gn = tile_n + nb + j * 16 + col;
    const int which = gn >> 10;
    const int d = gn & 1023;
    const int h = d >> 6, hi = d & 63;
    if (which != 1) {
      // Q/V -> transposed [bb][h][hi][s], packed f16x4 along s
      const float* bp = (which == 0) ? bias0 : bias2;
      f16* dst        = (which == 0) ? Qtp  : Vtp;
      const float bvv = bp[d];
      const float qs  = (which == 0) ? 0.18033688f : 1.0f;  // 1/sqrt(64)*log2(e) in Q
      #pragma unroll
      for (int i = 0; i < 4; ++i) {
        const int gm = tile_m + mb + i * 16 + quad * 4;   // r=0; s run of 4
        const int bb = gm >> 11, s = gm & 2047;
        f16x4 pw;
        #pragma unroll
        for (int r = 0; r < 4; ++r) pw[r] = (f16)((acc[i][j][r] + bvv) * qs);
        *(f16x4*)&dst[(((size_t)bb * 16 + h) * 64 + hi) * 2048 + s] = pw;
      }
    } else {
      const float bvv = bias1[d];
      #pragma unroll
      for (int i = 0; i < 4; ++i) {
        #pragma unroll
        for (int r = 0; r < 4; ++r) {
          const int gm = tile_m + mb + i * 16 + quad * 4 + r;
          const int bb = gm >> 11, s = gm & 2047;
          Kp[(((size_t)bb * 16 + h) * 2048 + s) * 64 + hi] = (f16)(acc[i][j][r] + bvv);
        }
      }
    }
  }
}

// ---------------- flash attention, merged tile-pair, static-max softmax ----
// Unchanged from R15/R16 (l-via-MFMA).
__global__ __launch_bounds__(256, 4) void attn_kernel(
    const f16* __restrict__ Qt, const f16* __restrict__ K, const f16* __restrict__ Vt,
    f16* __restrict__ ctx)
{
  __shared__ __align__(16) f16 Ks[2][64 * 72];     // [buf][kv][d], pad 72
  __shared__ __align__(16) f16 Vts[2][64 * 72];    // [buf][d][kv], pad 72
  __shared__ __align__(16) f16 Ps[4][2][16 * 72];  // per-wave, per-tile P

  const int bh  = blockIdx.x;                      // x = bh -> XCD = bh%8 (R6)
  const int yy  = blockIdx.y;
  const int p   = (yy < 8) ? yy : 23 - yy;         // CU pair (yy,yy+8): p+p'=15
  const int qlong = 31 - p, qshort = p;
  const int tid = threadIdx.x;
  const int wave = tid >> 6, lane = tid & 63;
  const int quad = lane >> 4, col = lane & 15;
  const int b = bh >> 4, h = bh & 15;
  const size_t base = (size_t)bh * 2048 * 64;
  const size_t vtb  = (size_t)bh * 64 * 2048;      // also Qt base stride

  // staging map: 512 16B-chunks per tensor, 2 per thread
  int srow[2], sc8[2];
  #pragma unroll
  for (int i = 0; i < 2; ++i) {
    const int flat = tid + i * 256;
    srow[i] = flat >> 3;
    sc8[i]  = (flat & 7) * 8;
  }

  const int qa = qlong * 64 + wave * 16;    // long tile rows (always active)
  const int qb = qshort * 64 + wave * 16;   // short tile rows (active t<=qshort)
  // Q fragments from transposed layout: element j at d = (quad*8+j), s = q
  f16x8 bqa0, bqa1, bqb0, bqb1;
  #pragma unroll
  for (int j = 0; j < 8; ++j) {
    const size_t r0 = vtb + (size_t)(quad * 8 + j) * 2048;
    const size_t r1 = vtb + (size_t)(32 + quad * 8 + j) * 2048;
    bqa0[j] = Qt[r0 + qa + col];
    bqa1[j] = Qt[r1 + qa + col];
    bqb0[j] = Qt[r0 + qb + col];
    bqb1[j] = Qt[r1 + qb + col];
  }

  // all-ones B-operand for the l-column MFMA
  f16x8 ones8;
  #pragma unroll
  for (int j = 0; j < 8; ++j) ones8[j] = (f16)1.f;

  f32x4 cta[4] = {}, ctb[4] = {};
  f32x4 zla = {}, zlb = {};                 // l accumulators (per-lane, no shuffles)

  f16x8 kr[2], vr[2];
  auto gload = [&](int t) {
    #pragma unroll
    for (int i = 0; i < 2; ++i) {
      kr[i] = *(const f16x8*)&K[base + (size_t)(t * 64 + srow[i]) * 64 + sc8[i]];
      vr[i] = *(const f16x8*)&Vt[vtb + (size_t)srow[i] * 2048 + t * 64 + sc8[i]];
    }
  };
  auto swrite = [&](int buf) {
    #pragma unroll
    for (int i = 0; i < 2; ++i) {
      *(f16x8*)&Ks[buf][srow[i] * 72 + sc8[i]]  = kr[i];
      *(f16x8*)&Vts[buf][srow[i] * 72 + sc8[i]] = vr[i];
    }
  };

  const int nIter = qlong + 1;               // 17..32

  // prologue: stage tile 0 into buf0, prefetch tile 1 into regs
  gload(0);
  __syncthreads();
  swrite(0);
  gload(1);                                  // nIter >= 17 always

  for (int t = 0; t < nIter; ++t) {
    const int cur = t & 1;
    __syncthreads();                         // buf[cur] staged; swrites drained
    const bool doB = (t <= qshort);

    // S^T = K Q^T for both tiles; ak frags shared from registers
    f32x4 sa[4], sb[4];
    __builtin_amdgcn_s_setprio(1);
    #pragma unroll
    for (int jt = 0; jt < 4; ++jt) {
      const int kro = (jt * 16 + col) * 72;
      const f16x8 ak0 = *(const f16x8*)&Ks[cur][kro + quad * 8];
      const f16x8 ak1 = *(const f16x8*)&Ks[cur][kro + 32 + quad * 8];
      f32x4 za = {};
      za = mfma16(ak0, bqa0, za);
      sa[jt] = mfma16(ak1, bqa1, za);
      if (doB) {
        f32x4 zb = {};
        zb = mfma16(ak0, bqb0, zb);
        sb[jt] = mfma16(ak1, bqb1, zb);
      }
    }
    __builtin_amdgcn_s_setprio(0);

    if (t == qlong) {   // long tile diagonal (last iteration)
      #pragma unroll
      for (int jt = 0; jt < 4; ++jt) {
        const int kg = t * 64 + jt * 16 + quad * 4;
        #pragma unroll
        for (int r = 0; r < 4; ++r)
          if (kg + r > qa + col) sa[jt][r] = -1e30f;
      }
    }
    if (t == qshort) {  // short tile diagonal
      #pragma unroll
      for (int jt = 0; jt < 4; ++jt) {
        const int kg = t * 64 + jt * 16 + quad * 4;
        #pragma unroll
        for (int r = 0; r < 4; ++r)
          if (kg + r > qb + col) sb[jt][r] = -1e30f;
      }
    }

    // ---- P = exp2(s) (static-max), long tile -> Ps slot 0 ----
    #pragma unroll
    for (int jt = 0; jt < 4; ++jt) {
      const f16x2 a01 = pkrtz(fexp2(sa[jt][0]), fexp2(sa[jt][1]));
      const f16x2 a23 = pkrtz(fexp2(sa[jt][2]), fexp2(sa[jt][3]));
      f16x4 pw; pw[0] = a01[0]; pw[1] = a01[1]; pw[2] = a23[0]; pw[3] = a23[1];
      *(f16x4*)&Ps[wave][0][col * 72 + jt * 16 + quad * 4] = pw;
    }

    // ---- P = exp2(s), short tile -> Ps slot 1 ----
    if (doB) {
      #pragma unroll
      for (int jt = 0; jt < 4; ++jt) {
        const f16x2 a01 = pkrtz(fexp2(sb[jt][0]), fexp2(sb[jt][1]));
        const f16x2 a23 = pkrtz(fexp2(sb[jt][2]), fexp2(sb[jt][3]));
        f16x4 pw; pw[0] = a01[0]; pw[1] = a01[1]; pw[2] = a23[0]; pw[3] = a23[1];
        *(f16x4*)&Ps[wave][1][col * 72 + jt * 16 + quad * 4] = pw;
      }
    }

    __asm__ volatile("s_waitcnt lgkmcnt(0)" ::: "memory");  // P RAW drain (no swrites in queue)

    // P fragments for PV + l
    const f16x8 apa0 = *(const f16x8*)&Ps[wave][0][col * 72 + quad * 8];
    const f16x8 apa1 = *(const f16x8*)&Ps[wave][0][col * 72 + 32 + quad * 8];

    // stage next tile + refill regs here: ds_writes overlap the PV phase,
    // drained by the next top-of-loop __syncthreads
    if (t + 1 < nIter) {
      swrite(cur ^ 1);
      if (t + 2 < nIter) gload(t + 2);
    }

    // ---- ctx += P V ; l += P @ 1 (matrix pipe) ----
    __builtin_amdgcn_s_setprio(1);
    zla = mfma16(apa1, ones8, mfma16(apa0, ones8, zla));
    if (doB) {
      const f16x8 apb0 = *(const f16x8*)&Ps[wave][1][col * 72 + quad * 8];
      const f16x8 apb1 = *(const f16x8*)&Ps[wave][1][col * 72 + 32 + quad * 8];
      zlb = mfma16(apb1, ones8, mfma16(apb0, ones8, zlb));
      #pragma unroll
      for (int jd = 0; jd < 4; ++jd) {
        const int vro = (jd * 16 + col) * 72;
        const f16x8 bv0 = *(const f16x8*)&Vts[cur][vro + quad * 8];
        const f16x8 bv1 = *(const f16x8*)&Vts[cur][vro + 32 + quad * 8];
        cta[jd] = mfma16(apa1, bv1, mfma16(apa0, bv0, cta[jd]));
        ctb[jd] = mfma16(apb1, bv1, mfma16(apb0, bv0, ctb[jd]));
      }
    } else {
      #pragma unroll
      for (int jd = 0; jd < 4; ++jd) {
        const int vro = (jd * 16 + col) * 72;
        const f16x8 bv0 = *(const f16x8*)&Vts[cur][vro + quad * 8];
        const f16x8 bv1 = *(const f16x8*)&Vts[cur][vro + 32 + quad * 8];
        cta[jd] = mfma16(apa1, bv1, mfma16(apa0, bv0, cta[jd]));
      }
    }
    __builtin_amdgcn_s_setprio(0);
  }

  // ---- epilogue: zl[r] = l[q=quad*4+r] directly (no shuffles) ----
  #pragma unroll
  for (int jd = 0; jd < 4; ++jd) {
    #pragma unroll
    for (int r = 0; r < 4; ++r) {
      const int qga = qa + quad * 4 + r;
      const int qgb = qb + quad * 4 + r;
      const int d = h * 64 + jd * 16 + col;
      ctx[((size_t)b * 2048 + qga) * 1024 + d] = (f16)(cta[jd][r] / zla[r]);
      ctx[((size_t)b * 2048 + qgb) * 1024 + d] = (f16)(ctb[jd][r] / zlb[r]);
    }
  }
}

// ---------------- O projection: 128x64, BK=64, reg-staged 2-phase pipeline -
// R17: same reg-staging discipline as gemm_qkv (R16, verified): regs = 3rd
// buffer, swrite(k+1) after barrier with a full iteration of vmcnt cover,
// compiler-scheduled (no asm fences). 6 f16x8 staging regs (+24 VGPR).
// LDS stays 48KB (2 blocks/CU, grid 512 = exactly 2/CU).
__global__ __launch_bounds__(256) void gemm_o(
    const f16* __restrict__ A, const f16* __restrict__ B, const float* __restrict__ bias,
    float* __restrict__ Out)
{
  constexpr int K = 1024;
  __shared__ __align__(16) f16 As[2][2][128 * 32];   // [buf][ks][row][32]
  __shared__ __align__(16) f16 Bs[2][2][64 * 32];    // [buf][ks][row][32]
  const int tid  = threadIdx.x;
  const int wave = tid >> 6, lane = tid & 63;
  const int quad = lane >> 4, col = lane & 15;
  const int tile_m = blockIdx.y * 128, tile_n = blockIdx.x * 64;
  const int mb = wave * 32;
  const int srow = lane >> 2, scol = (lane & 3) * 8;   // 16 rows x 32 cols per call
  const f16* gA = A + (size_t)(tile_m + srow) * K + scol;
  const f16* gB = B + (size_t)(tile_n + srow) * K + scol;
  const int loA = srow * 32 + scol;                    // lane offset within a 16-row slab
  const int loB = (wave * 16 + srow) * 32 + scol;

  f16x8 ra[2][2], rb[2];                    // [ks][i] A slabs, [ks] B slabs
  auto gload = [&](int k0) {
    #pragma unroll
    for (int ks = 0; ks < 2; ++ks) {
      #pragma unroll
      for (int i = 0; i < 2; ++i)
        ra[ks][i] = *(const f16x8*)(gA + (size_t)(wave * 32 + i * 16) * K + k0 + ks * 32);
      rb[ks] = *(const f16x8*)(gB + (size_t)(wave * 16) * K + k0 + ks * 32);
    }
  };
  auto swrite = [&](int buf) {
    #pragma unroll
    for (int ks = 0; ks < 2; ++ks) {
      #pragma unroll
      for (int i = 0; i < 2; ++i)
        *(f16x8*)&As[buf][ks][(wave * 32 + i * 16) * 32 + loA] = ra[ks][i];
      *(f16x8*)&Bs[buf][ks][loB] = rb[ks];
    }
  };

  f32x4 acc[2][4] = {};
  gload(0);
  swrite(0);
  gload(64);
  for (int k0 = 0; k0 < K; k0 += 64) {
    const int cur = (k0 >> 6) & 1;
    __syncthreads();                     // buf[cur] staged (lgkm drained)
    if (k0 + 64 < K) {
      swrite(cur ^ 1);                   // regs from prev iter; full-iter vmcnt cover
      if (k0 + 128 < K) gload(k0 + 128); // refill regs, 2 iterations ahead
    }
    #pragma unroll
    for (int ks = 0; ks < 2; ++ks) {
      f16x8 af[2], bf[4];
      #pragma unroll
      for (int i = 0; i < 2; ++i)
        af[i] = *(const f16x8*)&As[cur][ks][(mb + i * 16 + col) * 32 + quad * 8];
      #pragma unroll
      for (int j = 0; j < 4; ++j)
        bf[j] = *(const f16x8*)&Bs[cur][ks][(j * 16 + col) * 32 + quad * 8];
      #pragma unroll
      for (int i = 0; i < 2; ++i)
        #pragma unroll
        for (int j = 0; j < 4; ++j)
          acc[i][j] = mfma16(af[i], bf[j], acc[i][j]);
    }
  }

  #pragma unroll
  for (int j = 0; j < 4; ++j) {
    const int gn = tile_n + j * 16 + col;
    const float bvv = bias[gn];
    #pragma unroll
    for (int i = 0; i < 2; ++i) {
      #pragma unroll
      for (int r = 0; r < 4; ++r) {
        const int gm = tile_m + mb + i * 16 + quad * 4 + r;
        Out[(size_t)gm * 1024 + gn] = acc[i][j][r] + bvv;
      }
    }
  }
}

extern "C" void kernel_launch(void* const* d_in, const int* in_sizes, int n_in,
                              void* d_out, int out_size, void* d_ws, size_t ws_size,
                              hipStream_t stream)
{
  const float* x  = (const float*)d_in[0];
  const float* Wq = (const float*)d_in[1];
  const float* bq = (const float*)d_in[2];
  const float* Wk = (const float*)d_in[3];
  const float* bk = (const float*)d_in[4];
  const float* Wv = (const float*)d_in[5];
  const float* bv = (const float*)d_in[6];
  const float* Wo = (const float*)d_in[7];
  const float* bo = (const float*)d_in[8];
  float* out = (float*)d_out;

  f16* ws = (f16*)d_ws;
  const size_t M1 = 1048576;
  f16* xh    = ws;             // 4M halves
  f16* wqkvh = ws + 4  * M1;   // 3M
  f16* woh   = ws + 7  * M1;   // 1M
  f16* Qth   = ws + 8  * M1;   // 4M  [B,H,64,S] transposed, pre-scaled
  f16* Kh    = ws + 12 * M1;   // 4M  [B,H,S,64]
  f16* Vth   = ws + 20 * M1;   // 4M  [B,H,64,S] (written directly by gemm_qkv)
  f16* ctxh  = ws + 24 * M1;   // 4M  [B,S,D]

  cvt_kernel<<<4096, 256, 0, stream>>>(x, Wq, Wk, Wv, Wo, xh, wqkvh, woh);
  gemm_qkv<<<dim3(24, 32), 256, 0, stream>>>(xh, wqkvh, bq, bk, bv, Qth, Kh, Vth);
  attn_kernel<<<dim3(32, 16), 256, 0, stream>>>(Qth, Kh, Vth, ctxh);
  gemm_o<<<dim3(16, 32), 256, 0, stream>>>(ctxh, woh, bo, out);
}